// Round 2
// baseline (401.333 us; speedup 1.0000x reference)
//
#include <hip/hip_runtime.h>
#include <hip/hip_bf16.h>

// GCN 2-layer on MI355X — global-atomic-free CSR build + register-acc aggregation.
// R5: global atomicAdd walled ~24 ops/ns device-wide -> no global atomics.
// R6: bucketed LDS-atomic aggregation FAILED (no TLP + in-order LDS pipe).
// R7/R8: hist->scan->part->sort2 CSR + wave-per-node register-acc agg.
// R9/R10: MFMA gemm spill-bound at 98us (frag cache > VGPR budget).
// R11: LDS-free MFMA gemm -> gemm off top-5; agg1 89us @ 3.36 TB/s.
// R12: wide-gather agg1 REGRESSED: VMEM index loads entered the gather chain.
// R13: 512-node buckets: -15us on the partition pipeline.
// R14: deeper gather pipeline neutral -> agg1 is at a memory-PATH wall
//      (73% L2 miss on random 128B rows from a 12.8MB table), not latency.
// R15: harness feeds f32 -> replaced LDS-bound f32-fallback GEMM with
//      LDS-free MFMA via bf16 hi/lo split. -26us.
// R16: agg1 L2-residency rewrite. hb split into 4 quarter-tables
//      hbq[q][N][16] (3.2MB < 4MB per-XCD L2). Wave owns 16 nodes,
//      per-lane f32 register accumulators (lane=feature, static index),
//      quarter-MAJOR sweep so all resident waves hit the same 3.2MB table
//      -> gathers become L2 hits after ~102MB compulsory warmup (vs 300MB
//      misses/iter before). No partial buffer (workspace unchanged), no
//      grid sync (waves independent). 4 edges/gather-instr (16 lanes x 32B).
//      + merged prep kernels, merged gemm kernels (-2 launches), cheaper
//      truncate-hi/corrected-lo x-split (lo absorbs hi truncation error).

typedef short s8_t __attribute__((ext_vector_type(8)));
typedef float f4_t __attribute__((ext_vector_type(4)));

#define NPW 16  // nodes per wave in agg1

__device__ __forceinline__ float bf2f(unsigned short u) {
    union { unsigned int u; float f; } c; c.u = ((unsigned int)u) << 16; return c.f;
}
__device__ __forceinline__ unsigned short f2bf(float f) {
    union { float f; unsigned int u; } c; c.f = f;
    unsigned int u = c.u;
    unsigned int r = (u + 0x7fffu + ((u >> 16) & 1u)) >> 16;  // round-nearest-even
    return (unsigned short)r;
}
__device__ __forceinline__ float loadF(const void* p, int i, int isbf) {
    return isbf ? bf2f(((const unsigned short*)p)[i]) : ((const float*)p)[i];
}
__device__ __forceinline__ int edgeIdx(const void* e, long long i, int is64) {
    return is64 ? (int)((const long long*)e)[i] : ((const int*)e)[i];
}

// flags[0] = edge indices are int64; flags[1] = float tensors are bf16
__global__ void k_detect(const void* e, const void* x, int* flags) {
    int lane = threadIdx.x;  // blockDim = 64
    unsigned int ew = ((const unsigned int*)e)[2 * lane + 1];
    unsigned long long nz = __ballot(ew != 0);
    unsigned int xw = ((const unsigned int*)x)[lane];
    unsigned int low = xw & 0xffffu;
    unsigned int e8 = (low >> 7) & 0xffu;
    bool plaus = (low == 0u) || (e8 >= 110u && e8 <= 135u);
    unsigned long long pl = __ballot(plaus);
    if (lane == 0) {
        flags[0] = (nz == 0ull) ? 1 : 0;
        flags[1] = (__popcll(pl) > 32) ? 1 : 0;
    }
}

// Merged weight prep. bf16 mode: wT[n][k] = W1[k][n].
// f32 mode: transposed bf16 hi/lo pair wTh + wTl ~= W1^T (rne split).
__global__ void k_prep_all(const void* W1, unsigned short* __restrict__ wT,
                           unsigned short* __restrict__ wTh,
                           unsigned short* __restrict__ wTl, const int* flags) {
    int tid = threadIdx.x;
    if (flags[1]) {
        const unsigned short* w = (const unsigned short*)W1;
        for (int idx = tid; idx < 128 * 64; idx += 256) {
            int k = idx >> 6, n = idx & 63;
            wT[n * 128 + k] = w[idx];
        }
    } else {
        const float* w = (const float*)W1;
        for (int idx = tid; idx < 128 * 64; idx += 256) {
            int k = idx >> 6, n = idx & 63;
            float v = w[idx];
            unsigned short h = f2bf(v);
            wTh[n * 128 + k] = h;
            wTl[n * 128 + k] = f2bf(v - bf2f(h));
        }
    }
}

// Per-block LDS histogram over B coarse buckets (dst>>9); hist[bucket][block].
__launch_bounds__(256)
__global__ void k_hist(const void* e, int* __restrict__ histT, const int* flags,
                       int E, int B, int HB) {
    __shared__ int hist[1024];
    int tid = threadIdx.x;
    int is64 = flags[0];
    for (int f = tid; f < B; f += 256) hist[f] = 0;
    __syncthreads();
    int base = blockIdx.x * 4096;
    #pragma unroll
    for (int k = 0; k < 16; ++k) {
        int i = base + k * 256 + tid;
        if (i < E) {
            int d = edgeIdx(e, (long long)E + i, is64);
            atomicAdd(&hist[d >> 9], 1);   // LDS atomic
        }
    }
    __syncthreads();
    for (int f = tid; f < B; f += 256)
        histT[(long long)f * HB + blockIdx.x] = hist[f];
}

// Exclusive scan over M = B*HB ints, level A.
__global__ void k_scanA(int* __restrict__ data, int* __restrict__ partial, int M) {
    __shared__ int s[256];
    int tid = threadIdx.x;
    int i = blockIdx.x * 256 + tid;
    int v = (i < M) ? data[i] : 0;
    s[tid] = v; __syncthreads();
    for (int off = 1; off < 256; off <<= 1) {
        int t = (tid >= off) ? s[tid - off] : 0;
        __syncthreads(); s[tid] += t; __syncthreads();
    }
    if (i < M) data[i] = s[tid] - v;
    if (tid == 255) partial[blockIdx.x] = s[255];
}

// Level B: in-place exclusive scan of nP partials (nP <= 8192).
__global__ void k_scanB(int* __restrict__ partial, int nP) {
    __shared__ int s[1024];
    int tid = threadIdx.x;
    int C = (nP + 1023) >> 10;
    int base = tid * C;
    int v[8]; int tot = 0;
    for (int j = 0; j < C; ++j) { v[j] = (base + j < nP) ? partial[base + j] : 0; tot += v[j]; }
    s[tid] = tot; __syncthreads();
    for (int off = 1; off < 1024; off <<= 1) {
        int t = (tid >= off) ? s[tid - off] : 0;
        __syncthreads(); s[tid] += t; __syncthreads();
    }
    int run = s[tid] - tot;
    for (int j = 0; j < C; ++j) { if (base + j < nP) { int tmp = v[j]; partial[base + j] = run; run += tmp; } }
}

// Level C: add block bases; extract bucketStart.
__global__ void k_scanC(int* __restrict__ data, const int* __restrict__ partial,
                        int* __restrict__ bucketStart, int M, int HB, int B, int E) {
    int f = blockIdx.x * 256 + threadIdx.x;
    if (f < M) {
        int val = data[f] + partial[f >> 8];
        data[f] = val;
        int q = f / HB;
        if (f - q * HB == 0) bucketStart[q] = val;
    }
    if (f == 0) bucketStart[B] = E;
}

// Partition: pos = scanned[bucket][block] + LDS-atomic rank.
// part[pos] = src | (dstLocal << 17)   (requires N <= 2^17).
__launch_bounds__(256)
__global__ void k_part(const void* e, const int* __restrict__ histT,
                       int* __restrict__ part, const int* flags,
                       int E, int B, int HB) {
    __shared__ int lcur[1024];
    int tid = threadIdx.x;
    int is64 = flags[0];
    for (int f = tid; f < B; f += 256)
        lcur[f] = histT[(long long)f * HB + blockIdx.x];
    __syncthreads();
    int base = blockIdx.x * 4096;
    #pragma unroll
    for (int k = 0; k < 16; ++k) {
        int i = base + k * 256 + tid;
        if (i < E) {
            int s = edgeIdx(e, i, is64);
            int d = edgeIdx(e, (long long)E + i, is64);
            int pos = atomicAdd(&lcur[d >> 9], 1);   // LDS atomic
            part[pos] = s | ((d & 511) << 17);
        }
    }
}

// Block-per-bucket second sort (512 nodes/bucket).
__launch_bounds__(512)
__global__ void k_sort2(const int* __restrict__ part, const int* __restrict__ bucketStart,
                        int* __restrict__ srcSorted, int* __restrict__ start,
                        float* __restrict__ dinv, int N, int B) {
    __shared__ int cnt[512];
    __shared__ int s[512];
    __shared__ int cur[512];
    int tid = threadIdx.x, b = blockIdx.x;
    cnt[tid] = 0;
    __syncthreads();
    int lo = bucketStart[b], hi = bucketStart[b + 1];
    for (int idx = lo + tid; idx < hi; idx += 512)
        atomicAdd(&cnt[(part[idx] >> 17) & 511], 1);
    __syncthreads();
    int v = cnt[tid];
    s[tid] = v; __syncthreads();
    for (int off = 1; off < 512; off <<= 1) {
        int t = (tid >= off) ? s[tid - off] : 0;
        __syncthreads(); s[tid] += t; __syncthreads();
    }
    int base_ = lo + s[tid] - v;   // exclusive-scan position
    cur[tid] = base_;
    int node = b * 512 + tid;
    if (node < N) {
        start[node] = base_;
        dinv[node] = rsqrtf((float)(v + 1));  // +1 self-loop
    }
    if (b == 0 && tid == 0) start[N] = bucketStart[B];  // = E
    __syncthreads();
    for (int idx = lo + tid; idx < hi; idx += 512) {
        int pw = part[idx];
        int pos = atomicAdd(&cur[(pw >> 17) & 511], 1);  // LDS atomic w/ return
        srcSorted[pos] = pw & 0x1FFFF;
    }
}

// Merged MFMA GEMM, LDS-free, QUARTERED store layout (R16):
//   hbq[((nt*N + row)*16 + r] = bf16((x@W1)[row][nt*16+r] * dinv[row])
// bf16 input: direct. f32 input: truncate-hi / corrected-lo bf16 split,
// 3-term MFMA (xh*Wh + xl*Wh + xh*Wl); dropped xl*Wl ~ 2^-16 relative.
__launch_bounds__(256)
__global__ void k_gemm(const void* x, const unsigned short* __restrict__ wT,
                       const unsigned short* __restrict__ wTh,
                       const unsigned short* __restrict__ wTl,
                       const float* __restrict__ dinv,
                       unsigned short* __restrict__ hbq, const int* flags, int N) {
    int tid = threadIdx.x;
    int lane = tid & 63, wv = tid >> 6;
    int q = lane >> 4, r = lane & 15;
    int gw = blockIdx.x * 4 + wv;
    int nW = gridDim.x * 4;
    int RB = (N + 15) >> 4;
    int isbf = flags[1];
    for (int rb = gw; rb < RB; rb += nW) {
        int row0 = rb * 16;
        int arow = row0 + r;
        f4_t acc[4];
        #pragma unroll
        for (int nt = 0; nt < 4; ++nt) acc[nt] = (f4_t){0.f, 0.f, 0.f, 0.f};
        if (isbf) {
            const unsigned short* xb = (const unsigned short*)x;
            s8_t a[4];
            #pragma unroll
            for (int kk = 0; kk < 4; ++kk)
                a[kk] = (arow < N)
                    ? *(const s8_t*)&xb[(long long)arow * 128 + kk * 32 + q * 8]
                    : (s8_t)(short)0;
            #pragma unroll
            for (int nt = 0; nt < 4; ++nt) {
                #pragma unroll
                for (int kk = 0; kk < 4; ++kk) {
                    s8_t b = *(const s8_t*)&wT[(nt * 16 + r) * 128 + kk * 32 + q * 8];
                    acc[nt] = __builtin_amdgcn_mfma_f32_16x16x32_bf16(a[kk], b, acc[nt], 0, 0, 0);
                }
            }
        } else {
            const float* xf = (const float*)x;
            s8_t ah[4], al[4];
            #pragma unroll
            for (int kk = 0; kk < 4; ++kk) {
                f4_t x0 = (f4_t){0.f, 0.f, 0.f, 0.f}, x1 = x0;
                if (arow < N) {
                    const float* p = &xf[(long long)arow * 128 + kk * 32 + q * 8];
                    x0 = *(const f4_t*)p;
                    x1 = *(const f4_t*)(p + 4);
                }
                #pragma unroll
                for (int j = 0; j < 4; ++j) {
                    // truncate-hi: hi = top 16 bits; lo corrects the truncation.
                    union { float f; unsigned int u; } c0, h0, r0, c1, h1, r1;
                    c0.f = x0[j];
                    h0.u = c0.u & 0xffff0000u;
                    ah[kk][j] = (short)(c0.u >> 16);
                    r0.f = x0[j] - h0.f;
                    al[kk][j] = (short)(r0.u >> 16);
                    c1.f = x1[j];
                    h1.u = c1.u & 0xffff0000u;
                    ah[kk][4 + j] = (short)(c1.u >> 16);
                    r1.f = x1[j] - h1.f;
                    al[kk][4 + j] = (short)(r1.u >> 16);
                }
            }
            #pragma unroll
            for (int nt = 0; nt < 4; ++nt) {
                #pragma unroll
                for (int kk = 0; kk < 4; ++kk) {
                    s8_t bh = *(const s8_t*)&wTh[(nt * 16 + r) * 128 + kk * 32 + q * 8];
                    s8_t bl = *(const s8_t*)&wTl[(nt * 16 + r) * 128 + kk * 32 + q * 8];
                    acc[nt] = __builtin_amdgcn_mfma_f32_16x16x32_bf16(ah[kk], bh, acc[nt], 0, 0, 0);
                    acc[nt] = __builtin_amdgcn_mfma_f32_16x16x32_bf16(al[kk], bh, acc[nt], 0, 0, 0);
                    acc[nt] = __builtin_amdgcn_mfma_f32_16x16x32_bf16(ah[kk], bl, acc[nt], 0, 0, 0);
                }
            }
        }
        #pragma unroll
        for (int reg = 0; reg < 4; ++reg) {
            int row = row0 + q * 4 + reg;
            if (row < N) {
                float dv = dinv[row];
                #pragma unroll
                for (int nt = 0; nt < 4; ++nt)
                    hbq[((long long)nt * N + row) * 16 + r] = f2bf(acc[nt][reg] * dv);
            }
        }
    }
}

// R16 layer-1 aggregation: quarter-major L2-resident gather.
// Wave owns NPW nodes; lane = feature (g=lane>>4 -> quarter, r=lane&15).
// Pass q: all waves gather only from hbq[q] (3.2MB, per-XCD-L2-resident).
// Per gather instr: 4 edges (one per 16-lane group, 32B contiguous each).
// Partial sums live in registers (acc[i], statically indexed); epilogue
// (self-loop + b1 + relu + *W2 + reduce) fused after the 4 passes.
__launch_bounds__(256)
__global__ void k_agg1(const unsigned short* __restrict__ hbq,
                       const float* __restrict__ dinv,
                       const int* __restrict__ start,
                       const int* __restrict__ srcSorted,
                       const void* b1, const void* W2, float* __restrict__ sbuf2,
                       const int* flags, int N) {
    int lane = threadIdx.x & 63;
    int wid = (blockIdx.x * blockDim.x + threadIdx.x) >> 6;
    int g = lane >> 4, r = lane & 15;
    int n0 = wid * NPW;
    if (n0 >= N) return;
    float acc[NPW];
    #pragma unroll
    for (int i = 0; i < NPW; ++i) acc[i] = 0.f;
    for (int q = 0; q < 4; ++q) {
        const unsigned short* tab = hbq + (long long)q * N * 16;
        #pragma unroll
        for (int i = 0; i < NPW; ++i) {
            int node = n0 + i;
            if (node < N) {
                int base = start[node];
                int cnt  = start[node + 1] - base;
                float a = 0.f;
                for (int c = 0; c < cnt; c += 64) {
                    int t = c + lane;
                    int sidx = (t < cnt) ? srcSorted[base + t] : 0;
                    int m = cnt - c; if (m > 64) m = 64;
                    int t2 = 0;
                    for (; t2 + 16 <= m; t2 += 16) {
                        int e0 = __shfl(sidx, t2 + g);
                        int e1 = __shfl(sidx, t2 + 4 + g);
                        int e2 = __shfl(sidx, t2 + 8 + g);
                        int e3 = __shfl(sidx, t2 + 12 + g);
                        unsigned short v0 = tab[e0 * 16 + r];
                        unsigned short v1 = tab[e1 * 16 + r];
                        unsigned short v2 = tab[e2 * 16 + r];
                        unsigned short v3 = tab[e3 * 16 + r];
                        a += bf2f(v0); a += bf2f(v1);
                        a += bf2f(v2); a += bf2f(v3);
                    }
                    for (; t2 < m; t2 += 4) {
                        int e0 = __shfl(sidx, t2 + g);
                        unsigned short v0 = tab[e0 * 16 + r];
                        a += (t2 + g < m) ? bf2f(v0) : 0.f;
                    }
                }
                // sum the 4 groups' partials (lanes sharing r)
                a += __shfl_xor(a, 16);
                a += __shfl_xor(a, 32);
                acc[i] = (g == q) ? a : acc[i];  // deposit quarter q at its lanes
            }
        }
    }
    int isbf = flags[1];
    float b1v = loadF(b1, lane, isbf);
    float w2v = loadF(W2, lane, isbf);
    #pragma unroll
    for (int i = 0; i < NPW; ++i) {
        int node = n0 + i;
        if (node < N) {
            float di = dinv[node];
            // self-loop: feature f=lane lives in quarter g at offset r
            unsigned short sv = hbq[((long long)g * N + node) * 16 + r];
            float v = (acc[i] + bf2f(sv)) * di + b1v;
            v = fmaxf(v, 0.f);
            float p = v * w2v;
            #pragma unroll
            for (int o = 32; o >= 1; o >>= 1) p += __shfl_xor(p, o);
            if (lane == 0) sbuf2[node] = p * di;
        }
    }
}

// Layer-2: out[i] = (sum_src sbuf2[src] + sbuf2[i]) * dinv[i] + b2.
__launch_bounds__(256)
__global__ void k_agg2(const float* __restrict__ sbuf2, const float* __restrict__ dinv,
                       const int* __restrict__ start,
                       const int* __restrict__ srcSorted,
                       const void* b2, void* out, const int* flags, int N) {
    int lane = threadIdx.x & 63;
    int node = (blockIdx.x * blockDim.x + threadIdx.x) >> 6;
    if (node >= N) return;
    int isbf = flags[1];
    float di = dinv[node];
    int base = start[node], cnt = start[node + 1] - base;
    float part = 0.f;
    for (int t = lane; t < cnt; t += 64) part += sbuf2[srcSorted[base + t]];
    #pragma unroll
    for (int o = 32; o >= 1; o >>= 1) part += __shfl_xor(part, o);
    if (lane == 0) {
        float o_ = (part + sbuf2[node]) * di + loadF(b2, 0, isbf);
        if (isbf) ((unsigned short*)out)[node] = f2bf(o_);
        else      ((float*)out)[node] = o_;
    }
}

extern "C" void kernel_launch(void* const* d_in, const int* in_sizes, int n_in,
                              void* d_out, int out_size, void* d_ws, size_t ws_size,
                              hipStream_t stream) {
    const void* x  = d_in[0];
    const void* e  = d_in[1];
    const void* W1 = d_in[2];
    const void* b1 = d_in[3];
    const void* W2 = d_in[4];
    const void* b2 = d_in[5];
    int N = in_sizes[0] / 128;     // 100000
    int E = in_sizes[1] / 2;       // 3200000
    int B  = (N + 511) / 512;      // 196 buckets of 512 nodes
    int HB = (E + 4095) / 4096;    // 782 hist blocks
    int M  = B * HB;               // 153,272
    int nP = (M + 255) / 256;      // 599 (<=8192)
    int NB = B * 512;              // 100,352 padded nodes
    int EP = ((E + 255) / 256) * 256;
    int RB = (N + 15) / 16;        // 6250 row-blocks
    int GG = (RB + 3) / 4;         // 1563 blocks: one row-block per wave
    int AW = (RB + 3) / 4;         // agg1: ceil(N/NPW)=6250 waves -> 1563 blocks

    // Workspace (~27 MB; 40.4 MB proven safe, 52.8 MB crashes):
    int*   wsI         = (int*)d_ws;
    int*   flags       = wsI;                              // 256
    unsigned short* wT  = (unsigned short*)(wsI + 256);    // 8192 ushorts (16KB)
    unsigned short* wTh = (unsigned short*)(wsI + 256 + 4096);  // 8192 ushorts
    unsigned short* wTl = (unsigned short*)(wsI + 256 + 8192);  // 8192 ushorts
    int*   histT       = wsI + 256 + 12288;                // M rounded
    int*   partial     = histT + ((M + 255) / 256) * 256;  // nP rounded
    int*   bucketStart = partial + ((nP + 255) / 256) * 256;  // B+1 -> 1040
    float* dinv        = (float*)(bucketStart + 1040);     // NB
    float* sbuf2       = dinv + NB;                        // NB
    int*   start       = (int*)(sbuf2 + NB);               // NB + 256
    int*   srcSorted   = start + NB + 256;                 // EP
    int*   part        = srcSorted + EP;                   // EP (12.8 MB)
    unsigned short* hbq = (unsigned short*)part;           // 4*N*16 bf16, ALIASES part
                                                           // (N*128B = 12.800MB <= EP*4)

    hipLaunchKernelGGL(k_detect, dim3(1), dim3(64), 0, stream, e, x, flags);
    hipLaunchKernelGGL(k_prep_all, dim3(1), dim3(256), 0, stream, W1, wT, wTh, wTl, flags);
    hipLaunchKernelGGL(k_hist, dim3(HB), dim3(256), 0, stream, e, histT, flags, E, B, HB);
    hipLaunchKernelGGL(k_scanA, dim3(nP), dim3(256), 0, stream, histT, partial, M);
    hipLaunchKernelGGL(k_scanB, dim3(1), dim3(1024), 0, stream, partial, nP);
    hipLaunchKernelGGL(k_scanC, dim3(nP), dim3(256), 0, stream,
                       histT, partial, bucketStart, M, HB, B, E);
    hipLaunchKernelGGL(k_part, dim3(HB), dim3(256), 0, stream, e, histT, part, flags, E, B, HB);
    hipLaunchKernelGGL(k_sort2, dim3(B), dim3(512), 0, stream,
                       part, bucketStart, srcSorted, start, dinv, N, B);
    hipLaunchKernelGGL(k_gemm, dim3(GG), dim3(256), 0, stream,
                       x, wT, wTh, wTl, dinv, hbq, flags, N);
    hipLaunchKernelGGL(k_agg1, dim3(AW), dim3(256), 0, stream,
                       hbq, dinv, start, srcSorted, b1, W2, sbuf2, flags, N);
    hipLaunchKernelGGL(k_agg2, dim3((N + 3) / 4), dim3(256), 0, stream,
                       sbuf2, dinv, start, srcSorted, b2, d_out, flags, N);
}